// Round 19
// baseline (44.196 us; speedup 1.0000x reference)
//
#include <hip/hip_runtime.h>
#include <hip/hip_bf16.h>

// B=32, T=256, N=1024 -> R = 8192 rows, K = 1023 (padded 1024)
// alpha=0.5, b[m] = 1/(sqrt(m+1)+sqrt(m)), coef = sqrt(1023)/Gamma(1.5)
#define COEF 36.090511f
#define INV_COUNT (1.0f / 8388608.0f)   // 1 / (32*256*1024)

typedef __attribute__((ext_vector_type(4))) float f32x4;
typedef __attribute__((ext_vector_type(2))) unsigned long long u64x2;

typedef const __attribute__((address_space(1))) unsigned int* gas_ptr;
typedef __attribute__((address_space(3))) unsigned int* las_ptr;

__device__ __forceinline__ void load_lds16(const void* g, void* l) {
  __builtin_amdgcn_global_load_lds((gas_ptr)g, (las_ptr)l, 16, 0, 0);
}

// manual OCP e4m3fn decode (bias 7): exact
__device__ __forceinline__ float fp8_dec(unsigned int v) {
  const unsigned e = (v >> 3) & 0xF, m = v & 7;
  const int mant = e ? (8 + (int)m) : (int)m;
  const int ee = e ? (int)e : 1;
  float f = (float)mant * __int_as_float((ee + 117) << 23);  // mant * 2^(ee-10)
  return (v & 0x80) ? -f : f;
}

// Mt8d build: 8 dedup'd Toeplitz tiles [d][i'][j'] = fp8(b[d*128+i'-j']), 128KB total.
__global__ void mtb(unsigned char* __restrict__ Mt8d) {
  const int g = blockIdx.x * 1024 + threadIdx.x * 4;
  const int d = g >> 14;
  const int rem = g & 16383;
  const int ip = rem >> 7;
  const int j0 = rem & 127;
  float v[4];
#pragma unroll
  for (int e = 0; e < 4; e++) {
    int m = d * 128 + ip - (j0 + e);
    v[e] = 0.f;
    if (m >= 0) { float fm_ = (float)m; v[e] = 1.0f / (sqrtf(fm_ + 1.f) + sqrtf(fm_)); }
  }
  int w_ = __builtin_amdgcn_cvt_pk_fp8_f32(v[0], v[1], 0, false);
  w_ = __builtin_amdgcn_cvt_pk_fp8_f32(v[2], v[3], w_, true);
  *(unsigned int*)(Mt8d + g) = (unsigned int)w_;
}

// FUSED prep+gemm: no du8 array, no prep kernel. Each block RECOMPUTES its A-tile
// from u_pred at stage time (block-exclusive rows; u_pred panel L2-local: all 8 cb
// of one rb live on one XCD). cb==0 blocks (least K-work) also compute data-loss.
// 64x128 tile, BK=128, 8 waves (32x32), 1024 blocks, 32KB LDS -> 4 blocks/CU.
__launch_bounds__(512, 8)
__global__ void gemm(const float* __restrict__ up, const float* __restrict__ utr,
                     const unsigned char* __restrict__ Mt8d,
                     float* __restrict__ gpart) {
  __shared__ unsigned char sA[2][8192];    // [64 rows][128 k], quad-swizzled du (fp8)
  __shared__ unsigned char sB[16384];      // [128 cols][128 k], single-buffered
  __shared__ float wsum[8], wsumD[8];

  const int t = threadIdx.x;      // 512 threads = 8 waves
  const int w = t >> 6;
  const int lane = t & 63;

  const int bid = blockIdx.x;      // 0..1023
  const int xcd = bid & 7;
  const int local = bid >> 3;      // 0..127
  const int e = local & 1;
  const int j = local >> 1;        // 0..63
  const int h = (j < 32) ? (j & 7) : 7 - (j & 7);
  const int cb = e ? 7 - h : h;
  const int r16 = (((j >> 3) & 3) << 2) | (((j >> 5) & 1) << 1) | e;   // bijective
  const int rb = xcd * 16 + r16;   // XCD x owns rows [x*1024, +1024)
  const int row0 = rb * 64;
  const int col0 = cb * 128;
  const int nkb = cb + 1;          // K-blocks of 128 (triangular skip)

  const f32x4 vzero = {0.f, 0.f, 0.f, 0.f};
  f32x4 acc[2][2];
#pragma unroll
  for (int i = 0; i < 2; i++)
#pragma unroll
    for (int jj = 0; jj < 2; jj++) acc[i][jj] = vzero;

  // staging geometry: thread t -> (srow = t>>3, phys quad = t&7); src quad = phys^(srow&7)
  const int srow = t >> 3;                            // 0..63
  const int sq = ((t & 7) ^ (srow & 7)) * 16;         // pre-swizzled du-col window
  const float* uprow = up + (size_t)(row0 + srow) * 1024;
  const unsigned char* gB0 = Mt8d + srow * 128 + sq;

  // A-tile RECOMPUTE: load u_pred window [gc0, gc0+17), diff, fp8-pack, ds_write_b128.
  auto stageA = [&](int buf, int kb) {
    const int gc0 = kb * 128 + sq;
    const float* rp = uprow + gc0;
    f32x4 v0 = *(const f32x4*)(rp);
    f32x4 v1 = *(const f32x4*)(rp + 4);
    f32x4 v2 = *(const f32x4*)(rp + 8);
    f32x4 v3 = *(const f32x4*)(rp + 12);
    float u16 = (gc0 < 1008) ? rp[16] : 0.f;
    float d_[16];
    d_[0]=v0[1]-v0[0]; d_[1]=v0[2]-v0[1]; d_[2]=v0[3]-v0[2]; d_[3]=v1[0]-v0[3];
    d_[4]=v1[1]-v1[0]; d_[5]=v1[2]-v1[1]; d_[6]=v1[3]-v1[2]; d_[7]=v2[0]-v1[3];
    d_[8]=v2[1]-v2[0]; d_[9]=v2[2]-v2[1]; d_[10]=v2[3]-v2[2]; d_[11]=v3[0]-v2[3];
    d_[12]=v3[1]-v3[0]; d_[13]=v3[2]-v3[1]; d_[14]=v3[3]-v3[2]; d_[15]=u16-v3[3];
    if (gc0 == 1008) d_[15] = 0.f;         // du[1023] = 0 pad
    unsigned int pk[4];
#pragma unroll
    for (int q = 0; q < 4; q++) {
      int w_ = __builtin_amdgcn_cvt_pk_fp8_f32(d_[q*4+0], d_[q*4+1], 0, false);
      w_ = __builtin_amdgcn_cvt_pk_fp8_f32(d_[q*4+2], d_[q*4+3], w_, true);
      pk[q] = (unsigned int)w_;
    }
    *(u64x2*)&sA[buf][t * 16] = *(u64x2*)pk;
  };

  auto stageB = [&](int kb) {              // 2 global_load_lds (16KB tile, d = cb-kb)
    const size_t doff = (size_t)(cb - kb) * 16384;
#pragma unroll
    for (int l = 0; l < 2; l++)
      load_lds16(gB0 + doff + l * 64 * 128, (void*)&sB[l * 8192 + t * 16]);
  };

  const int wm = w >> 2, wn = w & 3;       // wave tile: rows wm*32, cols wn*32
  const int frow = lane & 15;
  const int g4 = lane >> 4;

  auto compute = [&](int buf) {
#pragma unroll
    for (int p = 0; p < 2; p++) {
      const int lq = g4 * 2 + p;
      const int ph = lq ^ (frow & 7);
      u64x2 aV[2], bV[2];
#pragma unroll
      for (int fm = 0; fm < 2; fm++)
        aV[fm] = *(const u64x2*)&sA[buf][(wm * 32 + fm * 16 + frow) * 128 + ph * 16];
#pragma unroll
      for (int fn = 0; fn < 2; fn++)
        bV[fn] = *(const u64x2*)&sB[(wn * 32 + fn * 16 + frow) * 128 + ph * 16];
#pragma unroll
      for (int fm = 0; fm < 2; fm++)
#pragma unroll
        for (int fn = 0; fn < 2; fn++) {
          acc[fm][fn] = __builtin_amdgcn_mfma_f32_16x16x32_fp8_fp8(
              (long long)aV[fm].x, (long long)bV[fn].x, acc[fm][fn], 0, 0, 0);
          acc[fm][fn] = __builtin_amdgcn_mfma_f32_16x16x32_fp8_fp8(
              (long long)aV[fm].y, (long long)bV[fn].y, acc[fm][fn], 0, 0, 0);
        }
    }
  };

  stageA(0, 0);                            // prologue: A(0) recompute into sA[0]
  for (int kb = 0; kb < nkb; kb++) {
    // BARRIER A: compute(kb-1) done -> sB free; sA[(kb+1)&1] free to overwrite
    asm volatile("" ::: "memory");
    __builtin_amdgcn_s_barrier();
    asm volatile("" ::: "memory");
    stageB(kb);                                        // issue B(kb) (2 lds-direct loads)
    if (kb + 1 < nkb) stageA((kb + 1) & 1, kb + 1);    // recompute A(kb+1) (hides B latency)
    asm volatile("s_waitcnt vmcnt(0)" ::: "memory");   // B(kb) arrived (f32 loads already drained)
    asm volatile("s_waitcnt lgkmcnt(0)" ::: "memory"); // own A ds_writes complete
    // BARRIER B: tile kb fully resident
    __builtin_amdgcn_s_barrier();
    asm volatile("" ::: "memory");
    compute(kb & 1);
  }

  // fused epilogue: C/D layout col = lane&15, row = (lane>>4)*4 + reg  [HW-verified].
  // du bytes from LAST A-tile in LDS: byte (rt,c) at rt*128 + ((c>>4)^(rt&7))*16 + (c&15).
  // Neighbor (c+1) via __shfl_down; frow==15: LDS (c<127) or recompute from u_pred (c==127).
  const int lastBuf = (nkb - 1) & 1;
  float psum = 0.f;
#pragma unroll
  for (int fm = 0; fm < 2; fm++) {
#pragma unroll
    for (int fn = 0; fn < 2; fn++) {
      const int c = wn * 32 + fn * 16 + frow;
      const int icol = col0 + c;                 // du index i; output position n = i+1
#pragma unroll
      for (int reg = 0; reg < 4; reg++) {
        const int rt = wm * 32 + fm * 16 + g4 * 4 + reg;
        float dui = fp8_dec(sA[lastBuf][rt * 128 + (((c >> 4) ^ (rt & 7)) << 4) + (c & 15)]);
        float dnext = __shfl_down(dui, 1, 64);
        if (frow == 15) {
          if (c == 127) {                        // tile edge: recompute du[icol+1] from u_pred
            if (icol < 1022) {
              const float* rr = up + (size_t)(row0 + rt) * 1024 + icol + 1;
              dnext = rr[1] - rr[0];             // f32 diff (vs fp8 elsewhere: tiny, safe)
            } else dnext = 0.f;
          } else {
            const int c1 = c + 1;
            dnext = fp8_dec(sA[lastBuf][rt * 128 + (((c1 >> 4) ^ (rt & 7)) << 4) + (c1 & 15)]);
          }
        }
        if (icol < 1023) {
          float frac = COEF * acc[fm][fn][reg];
          float ut = (icol == 1022) ? dui : 0.5f * (dui + dnext);
          float res = ut - frac;
          psum += res * res;
        }
      }
    }
  }

  // cb==0 block extras (least K-work): n=0 physics terms + data-loss for its 64 rows
  float dsum = 0.f;
  if (cb == 0) {
    if (t < 64) {                                // du[rt,0]^2 from sA[0] (tile kb=0)
      float d0 = fp8_dec(sA[lastBuf][t * 128 + ((t & 7) << 4)]);
      psum += d0 * d0;                           // t<64 = wave 0 -> lands in wsum[0]
    }
    const float* upr = up + (size_t)(row0 + (t >> 3)) * 1024 + (t & 7) * 4;
    const float* utr_ = utr + (size_t)(row0 + (t >> 3)) * 1024 + (t & 7) * 4;
#pragma unroll 4
    for (int i = 0; i < 32; i++) {               // 64 rows x 1024 cols, coalesced 128B/grp
      f32x4 a4 = *(const f32x4*)(upr + i * 32);
      f32x4 b4 = *(const f32x4*)(utr_ + i * 32);
      float e0 = a4[0]-b4[0], e1 = a4[1]-b4[1], e2 = a4[2]-b4[2], e3 = a4[3]-b4[3];
      dsum += e0*e0 + e1*e1 + e2*e2 + e3*e3;
    }
  }

#pragma unroll
  for (int off = 32; off > 0; off >>= 1) {
    psum += __shfl_down(psum, off, 64);
    dsum += __shfl_down(dsum, off, 64);
  }
  if (lane == 0) { wsum[w] = psum; wsumD[w] = dsum; }
  __syncthreads();
  if (t == 0) {
    float s = 0.f, sd = 0.f;
#pragma unroll
    for (int i = 0; i < 8; i++) { s += wsum[i]; sd += wsumD[i]; }
    gpart[bid] = s;
    gpart[1024 + bid] = sd;    // 0 for cb != 0
  }
}

// Single-block reduction of 2048 partials -> 3 outputs.
__global__ void finalize(const float* __restrict__ gpart, float* __restrict__ out) {
  const int t = threadIdx.x;    // 256 threads
  float ds = 0.f, ps = 0.f;
  for (int i = t; i < 1024; i += 256) { ps += gpart[i]; ds += gpart[1024 + i]; }

#pragma unroll
  for (int off = 32; off > 0; off >>= 1) {
    ds += __shfl_down(ds, off, 64);
    ps += __shfl_down(ps, off, 64);
  }
  __shared__ float sd[4], sp[4];
  const int lane = t & 63, w = t >> 6;
  if (lane == 0) { sd[w] = ds; sp[w] = ps; }
  __syncthreads();
  if (t == 0) {
    float data = (sd[0] + sd[1] + sd[2] + sd[3]) * INV_COUNT;
    float phys = (sp[0] + sp[1] + sp[2] + sp[3]) * INV_COUNT;
    out[0] = data + 0.1f * phys;
    out[1] = data;
    out[2] = phys;
  }
}

extern "C" void kernel_launch(void* const* d_in, const int* in_sizes, int n_in,
                              void* d_out, int out_size, void* d_ws, size_t ws_size,
                              hipStream_t stream) {
  const float* u_pred = (const float*)d_in[0];
  const float* u_true = (const float*)d_in[1];
  float* out = (float*)d_out;

  char* ws = (char*)d_ws;
  float* gpart = (float*)ws;                                    // 2048 floats (8 KiB)
  unsigned char* Mt8d = (unsigned char*)(ws + 131072);          // 8 tiles * 16 KiB = 128 KiB

  mtb<<<128, 256, 0, stream>>>(Mt8d);
  gemm<<<1024, 512, 0, stream>>>(u_pred, u_true, Mt8d, gpart);
  finalize<<<1, 256, 0, stream>>>(gpart, out);
}